// Round 1
// baseline (1729.422 us; speedup 1.0000x reference)
//
#include <hip/hip_runtime.h>

#define NN 50000
#define EE 800000
#define D_IN 128
#define H1 128
#define H2 64

// One 64-lane wave per edge. Each lane handles 2 consecutive floats (float2).
__global__ __launch_bounds__(256) void scatter_add_128(
    const float* __restrict__ feat, const int* __restrict__ src,
    const int* __restrict__ dst, float* __restrict__ agg,
    float* __restrict__ deg, int E, int with_deg)
{
    int gid = blockIdx.x * blockDim.x + threadIdx.x;
    int e = gid >> 6;
    int lane = gid & 63;
    if (e >= E) return;
    int s = src[e];
    int d = dst[e];
    const float2* frow = (const float2*)(feat + (size_t)s * D_IN);
    float2 v = frow[lane];
    float* arow = agg + (size_t)d * D_IN;
    atomicAdd(&arow[lane * 2], v.x);
    atomicAdd(&arow[lane * 2 + 1], v.y);
    if (with_deg && lane == 0) atomicAdd(&deg[d], 1.0f);
}

// h = relu(aggn @ Wl1 + bl1 + x @ Wr1); 2 rows x 128 cols per 256-thread block
__global__ __launch_bounds__(256) void sage_layer1(
    const float* __restrict__ x, const float* __restrict__ agg,
    const float* __restrict__ deg, const float* __restrict__ Wl,
    const float* __restrict__ bl, const float* __restrict__ Wr,
    float* __restrict__ h, int n)
{
    __shared__ float s_a[2][D_IN];
    __shared__ float s_x[2][D_IN];
    int col = threadIdx.x & 127;
    int r = threadIdx.x >> 7;              // 0..1
    int row = blockIdx.x * 2 + r;
    if (row < n) {
        float inv = 1.0f / fmaxf(deg[row], 1.0f);
        s_a[r][col] = agg[(size_t)row * D_IN + col] * inv;
        s_x[r][col] = x[(size_t)row * D_IN + col];
    }
    __syncthreads();
    if (row >= n) return;
    float acc = bl[col];
    #pragma unroll 8
    for (int k = 0; k < D_IN; ++k) {
        acc += s_a[r][k] * Wl[k * H1 + col] + s_x[r][k] * Wr[k * H1 + col];
    }
    h[(size_t)row * H1 + col] = fmaxf(acc, 0.0f);
}

// out = agg2n @ Wl2 + bl2 + h @ Wr2; 4 rows x 64 cols per 256-thread block
__global__ __launch_bounds__(256) void sage_layer2(
    const float* __restrict__ h, const float* __restrict__ agg,
    const float* __restrict__ deg, const float* __restrict__ Wl,
    const float* __restrict__ bl, const float* __restrict__ Wr,
    float* __restrict__ out, int n)
{
    __shared__ float s_a[4][H1];
    __shared__ float s_h[4][H1];
    int col = threadIdx.x & 63;
    int r = threadIdx.x >> 6;              // 0..3
    int row = blockIdx.x * 4 + r;
    if (row < n) {
        float inv = 1.0f / fmaxf(deg[row], 1.0f);
        s_a[r][col]      = agg[(size_t)row * H1 + col] * inv;
        s_a[r][col + 64] = agg[(size_t)row * H1 + col + 64] * inv;
        s_h[r][col]      = h[(size_t)row * H1 + col];
        s_h[r][col + 64] = h[(size_t)row * H1 + col + 64];
    }
    __syncthreads();
    if (row >= n) return;
    float acc = bl[col];
    #pragma unroll 8
    for (int k = 0; k < H1; ++k) {
        acc += s_a[r][k] * Wl[k * H2 + col] + s_h[r][k] * Wr[k * H2 + col];
    }
    out[(size_t)row * H2 + col] = acc;
}

extern "C" void kernel_launch(void* const* d_in, const int* in_sizes, int n_in,
                              void* d_out, int out_size, void* d_ws, size_t ws_size,
                              hipStream_t stream) {
    const float* x   = (const float*)d_in[0];
    const float* Wl1 = (const float*)d_in[1];
    const float* bl1 = (const float*)d_in[2];
    const float* Wr1 = (const float*)d_in[3];
    const float* Wl2 = (const float*)d_in[4];
    const float* bl2 = (const float*)d_in[5];
    const float* Wr2 = (const float*)d_in[6];
    const int*   ei  = (const int*)d_in[7];

    const int n = in_sizes[0] / D_IN;      // 50000
    const int E = in_sizes[7] / 2;         // 800000
    const int* src = ei;
    const int* dst = ei + E;

    float* out = (float*)d_out;
    char* ws = (char*)d_ws;
    const size_t agg_bytes = (size_t)n * D_IN * sizeof(float);
    float* agg = (float*)ws;                              // n*128 f32
    float* h   = (float*)(ws + agg_bytes);                // n*128 f32
    float* deg = (float*)(ws + 2 * agg_bytes);            // n f32

    hipMemsetAsync(agg, 0, agg_bytes, stream);
    hipMemsetAsync(deg, 0, (size_t)n * sizeof(float), stream);

    {
        long long total = (long long)E * 64;
        int blocks = (int)((total + 255) / 256);
        scatter_add_128<<<blocks, 256, 0, stream>>>(x, src, dst, agg, deg, E, 1);
    }
    sage_layer1<<<(n + 1) / 2, 256, 0, stream>>>(x, agg, deg, Wl1, bl1, Wr1, h, n);

    hipMemsetAsync(agg, 0, agg_bytes, stream);
    {
        long long total = (long long)E * 64;
        int blocks = (int)((total + 255) / 256);
        scatter_add_128<<<blocks, 256, 0, stream>>>(h, src, dst, agg, deg, E, 0);
    }
    sage_layer2<<<(n + 3) / 4, 256, 0, stream>>>(h, agg, deg, Wl2, bl2, Wr2, out, n);
}

// Round 2
// 690.996 us; speedup vs baseline: 2.5028x; 2.5028x over previous
//
#include <hip/hip_runtime.h>

#define D_IN 128
#define H1 128
#define H2 64

// ---- CSR build -------------------------------------------------------------

__global__ __launch_bounds__(256) void hist_dst(
    const int* __restrict__ dst, int* __restrict__ cnt, int E)
{
    int e = blockIdx.x * blockDim.x + threadIdx.x;
    if (e < E) atomicAdd(&cnt[dst[e]], 1);
}

// single-block exclusive scan over cnt[0..n) -> row_ptr[0..n], cursor[0..n)
__global__ __launch_bounds__(256) void scan_rowptr(
    const int* __restrict__ cnt, int* __restrict__ row_ptr,
    int* __restrict__ cursor, int n)
{
    __shared__ int s_part[256];
    __shared__ int s_off[256];
    int t = threadIdx.x;
    int chunk = (n + 255) / 256;
    int lo = t * chunk, hi = min(lo + chunk, n);
    int sum = 0;
    for (int i = lo; i < hi; ++i) sum += cnt[i];
    s_part[t] = sum;
    __syncthreads();
    if (t == 0) {
        int run = 0;
        for (int i = 0; i < 256; ++i) { s_off[i] = run; run += s_part[i]; }
        row_ptr[n] = run;  // == E
    }
    __syncthreads();
    int run = s_off[t];
    for (int i = lo; i < hi; ++i) {
        row_ptr[i] = run;
        cursor[i] = run;
        run += cnt[i];
    }
}

__global__ __launch_bounds__(256) void fill_csr(
    const int* __restrict__ src, const int* __restrict__ dst,
    int* __restrict__ cursor, int* __restrict__ ebuf, int E)
{
    int e = blockIdx.x * blockDim.x + threadIdx.x;
    if (e >= E) return;
    int pos = atomicAdd(&cursor[dst[e]], 1);
    ebuf[pos] = src[e];
}

// ---- gather mean-aggregate (D=128, one 64-lane wave per node) --------------

__global__ __launch_bounds__(256) void csr_mean_agg128(
    const float* __restrict__ feat, const int* __restrict__ row_ptr,
    const int* __restrict__ ebuf, float* __restrict__ agg, int n)
{
    int gid = blockIdx.x * blockDim.x + threadIdx.x;
    int node = gid >> 6;
    int lane = gid & 63;
    if (node >= n) return;
    int start = row_ptr[node];
    int end = row_ptr[node + 1];
    float ax = 0.0f, ay = 0.0f;
    for (int j0 = start; j0 < end; j0 += 64) {
        int m = min(64, end - j0);
        int myid = (lane < m) ? ebuf[j0 + lane] : 0;
        #pragma unroll 4
        for (int j = 0; j < m; ++j) {
            int s = __shfl(myid, j);
            float2 v = ((const float2*)(feat + (size_t)s * D_IN))[lane];
            ax += v.x; ay += v.y;
        }
    }
    float inv = 1.0f / fmaxf((float)(end - start), 1.0f);
    ((float2*)(agg + (size_t)node * D_IN))[lane] = make_float2(ax * inv, ay * inv);
}

// ---- layers ----------------------------------------------------------------

// h = relu(aggn @ Wl1 + bl1 + x @ Wr1); agg pre-normalized
__global__ __launch_bounds__(256) void sage_layer1(
    const float* __restrict__ x, const float* __restrict__ agg,
    const float* __restrict__ Wl, const float* __restrict__ bl,
    const float* __restrict__ Wr, float* __restrict__ h, int n)
{
    __shared__ float s_a[2][D_IN];
    __shared__ float s_x[2][D_IN];
    int col = threadIdx.x & 127;
    int r = threadIdx.x >> 7;
    int row = blockIdx.x * 2 + r;
    if (row < n) {
        s_a[r][col] = agg[(size_t)row * D_IN + col];
        s_x[r][col] = x[(size_t)row * D_IN + col];
    }
    __syncthreads();
    if (row >= n) return;
    float acc = bl[col];
    #pragma unroll 8
    for (int k = 0; k < D_IN; ++k) {
        acc += s_a[r][k] * Wl[k * H1 + col] + s_x[r][k] * Wr[k * H1 + col];
    }
    h[(size_t)row * H1 + col] = fmaxf(acc, 0.0f);
}

// out = agg2n @ Wl2 + bl2 + h @ Wr2
__global__ __launch_bounds__(256) void sage_layer2(
    const float* __restrict__ h, const float* __restrict__ agg,
    const float* __restrict__ Wl, const float* __restrict__ bl,
    const float* __restrict__ Wr, float* __restrict__ out, int n)
{
    __shared__ float s_a[4][H1];
    __shared__ float s_h[4][H1];
    int col = threadIdx.x & 63;
    int r = threadIdx.x >> 6;
    int row = blockIdx.x * 4 + r;
    if (row < n) {
        s_a[r][col]      = agg[(size_t)row * H1 + col];
        s_a[r][col + 64] = agg[(size_t)row * H1 + col + 64];
        s_h[r][col]      = h[(size_t)row * H1 + col];
        s_h[r][col + 64] = h[(size_t)row * H1 + col + 64];
    }
    __syncthreads();
    if (row >= n) return;
    float acc = bl[col];
    #pragma unroll 8
    for (int k = 0; k < H1; ++k) {
        acc += s_a[r][k] * Wl[k * H2 + col] + s_h[r][k] * Wr[k * H2 + col];
    }
    out[(size_t)row * H2 + col] = acc;
}

// ----------------------------------------------------------------------------

extern "C" void kernel_launch(void* const* d_in, const int* in_sizes, int n_in,
                              void* d_out, int out_size, void* d_ws, size_t ws_size,
                              hipStream_t stream) {
    const float* x   = (const float*)d_in[0];
    const float* Wl1 = (const float*)d_in[1];
    const float* bl1 = (const float*)d_in[2];
    const float* Wr1 = (const float*)d_in[3];
    const float* Wl2 = (const float*)d_in[4];
    const float* bl2 = (const float*)d_in[5];
    const float* Wr2 = (const float*)d_in[6];
    const int*   ei  = (const int*)d_in[7];

    const int n = in_sizes[0] / D_IN;      // 50000
    const int E = in_sizes[7] / 2;         // 800000
    const int* src = ei;
    const int* dst = ei + E;

    float* out = (float*)d_out;
    char* ws = (char*)d_ws;
    size_t off = 0;
    const size_t feat_bytes = (size_t)n * D_IN * sizeof(float);
    float* agg     = (float*)(ws + off); off += feat_bytes;
    float* h       = (float*)(ws + off); off += feat_bytes;
    int*   row_ptr = (int*)(ws + off);   off += (size_t)(n + 1) * sizeof(int);
    int*   cursor  = (int*)(ws + off);   off += (size_t)n * sizeof(int);
    int*   cnt     = (int*)(ws + off);   off += (size_t)n * sizeof(int);
    int*   ebuf    = (int*)(ws + off);   off += (size_t)E * sizeof(int);

    // ---- CSR build (once; shared by both layers) ----
    hipMemsetAsync(cnt, 0, (size_t)n * sizeof(int), stream);
    hist_dst<<<(E + 255) / 256, 256, 0, stream>>>(dst, cnt, E);
    scan_rowptr<<<1, 256, 0, stream>>>(cnt, row_ptr, cursor, n);
    fill_csr<<<(E + 255) / 256, 256, 0, stream>>>(src, dst, cursor, ebuf, E);

    // ---- layer 1 ----
    {
        long long total = (long long)n * 64;
        csr_mean_agg128<<<(int)((total + 255) / 256), 256, 0, stream>>>(
            x, row_ptr, ebuf, agg, n);
    }
    sage_layer1<<<(n + 1) / 2, 256, 0, stream>>>(x, agg, Wl1, bl1, Wr1, h, n);

    // ---- layer 2 ----
    {
        long long total = (long long)n * 64;
        csr_mean_agg128<<<(int)((total + 255) / 256), 256, 0, stream>>>(
            h, row_ptr, ebuf, agg, n);
    }
    sage_layer2<<<(n + 3) / 4, 256, 0, stream>>>(h, agg, Wl2, bl2, Wr2, out, n);
}

// Round 3
// 519.997 us; speedup vs baseline: 3.3258x; 1.3288x over previous
//
#include <hip/hip_runtime.h>

#define D 128

// ---- CSR build -------------------------------------------------------------

__global__ __launch_bounds__(256) void hist_dst(
    const int* __restrict__ dst, int* __restrict__ cnt, int E)
{
    int e = blockIdx.x * blockDim.x + threadIdx.x;
    if (e < E) atomicAdd(&cnt[dst[e]], 1);
}

__global__ __launch_bounds__(256) void scan_rowptr(
    const int* __restrict__ cnt, int* __restrict__ row_ptr,
    int* __restrict__ cursor, int n)
{
    __shared__ int s_part[256];
    __shared__ int s_off[256];
    int t = threadIdx.x;
    int chunk = (n + 255) / 256;
    int lo = t * chunk, hi = min(lo + chunk, n);
    int sum = 0;
    for (int i = lo; i < hi; ++i) sum += cnt[i];
    s_part[t] = sum;
    __syncthreads();
    if (t == 0) {
        int run = 0;
        for (int i = 0; i < 256; ++i) { s_off[i] = run; run += s_part[i]; }
        row_ptr[n] = run;
    }
    __syncthreads();
    int run = s_off[t];
    for (int i = lo; i < hi; ++i) {
        row_ptr[i] = run;
        cursor[i] = run;
        run += cnt[i];
    }
}

__global__ __launch_bounds__(256) void fill_csr(
    const int* __restrict__ src, const int* __restrict__ dst,
    int* __restrict__ cursor, int* __restrict__ ebuf, int E)
{
    int e = blockIdx.x * blockDim.x + threadIdx.x;
    if (e >= E) return;
    int pos = atomicAdd(&cursor[dst[e]], 1);
    ebuf[pos] = src[e];
}

// ---- gather mean-aggregate (D=128, one 64-lane wave per node) --------------

__global__ __launch_bounds__(256) void csr_mean_agg128(
    const float* __restrict__ feat, const int* __restrict__ row_ptr,
    const int* __restrict__ ebuf, float* __restrict__ agg, int n)
{
    int gid = blockIdx.x * blockDim.x + threadIdx.x;
    int node = gid >> 6;
    int lane = gid & 63;
    if (node >= n) return;
    int start = row_ptr[node];
    int end = row_ptr[node + 1];
    float ax = 0.0f, ay = 0.0f;
    for (int j0 = start; j0 < end; j0 += 64) {
        int m = min(64, end - j0);
        int myid = (lane < m) ? ebuf[j0 + lane] : 0;
        #pragma unroll 4
        for (int j = 0; j < m; ++j) {
            int s = __shfl(myid, j);
            float2 v = ((const float2*)(feat + (size_t)s * D))[lane];
            ax += v.x; ay += v.y;
        }
    }
    float inv = 1.0f / fmaxf((float)(end - start), 1.0f);
    ((float2*)(agg + (size_t)node * D))[lane] = make_float2(ax * inv, ay * inv);
}

// ---- layer 1 GEMM: h = relu([agg|x] @ [Wl;Wr] + bl), 128x128 tile ----------

__global__ __launch_bounds__(256) void sage_gemm1(
    const float* __restrict__ agg, const float* __restrict__ x,
    const float* __restrict__ Wl, const float* __restrict__ Wr,
    const float* __restrict__ bl, float* __restrict__ h, int n)
{
    __shared__ float As[128][33];   // pad 33: 8-row stride -> banks +8 apart
    __shared__ float Ws[32][132];   // pad 132: keeps 16B store alignment
    const int tid = threadIdx.x;
    const int tx = tid & 15;        // col group (cols tx + 16j)
    const int ty = tid >> 4;        // row group (rows ty*8 + i)
    const int row0 = blockIdx.x * 128;

    const int srow = tid >> 1;          // A-staging row 0..127
    const int sseg = (tid & 1) * 16;    // A-staging col seg
    const int wkk  = tid >> 3;          // W-staging k row 0..31
    const int wseg = (tid & 7) * 16;    // W-staging col seg

    float acc[8][8];
    #pragma unroll
    for (int i = 0; i < 8; ++i)
        #pragma unroll
        for (int j = 0; j < 8; ++j) acc[i][j] = 0.0f;

    for (int c = 0; c < 8; ++c) {
        const float* Asrc = (c < 4) ? agg : x;
        const float* Wsrc = (c < 4) ? Wl : Wr;
        const int k0 = (c & 3) * 32;

        int gr = row0 + srow; if (gr >= n) gr = n - 1;
        const float4* ap = (const float4*)(Asrc + (size_t)gr * D + k0 + sseg);
        float4 a0 = ap[0], a1 = ap[1], a2 = ap[2], a3 = ap[3];
        const float4* wp = (const float4*)(Wsrc + (size_t)(k0 + wkk) * 128 + wseg);
        float4 w0 = wp[0], w1 = wp[1], w2 = wp[2], w3 = wp[3];

        __syncthreads();   // previous chunk's reads complete
        {
            float* ad = &As[srow][sseg];
            ad[0]=a0.x; ad[1]=a0.y; ad[2]=a0.z; ad[3]=a0.w;
            ad[4]=a1.x; ad[5]=a1.y; ad[6]=a1.z; ad[7]=a1.w;
            ad[8]=a2.x; ad[9]=a2.y; ad[10]=a2.z; ad[11]=a2.w;
            ad[12]=a3.x; ad[13]=a3.y; ad[14]=a3.z; ad[15]=a3.w;
            float* wd = &Ws[wkk][wseg];
            wd[0]=w0.x; wd[1]=w0.y; wd[2]=w0.z; wd[3]=w0.w;
            wd[4]=w1.x; wd[5]=w1.y; wd[6]=w1.z; wd[7]=w1.w;
            wd[8]=w2.x; wd[9]=w2.y; wd[10]=w2.z; wd[11]=w2.w;
            wd[12]=w3.x; wd[13]=w3.y; wd[14]=w3.z; wd[15]=w3.w;
        }
        __syncthreads();

        #pragma unroll 8
        for (int kk = 0; kk < 32; ++kk) {
            float av[8], wv[8];
            #pragma unroll
            for (int i = 0; i < 8; ++i) av[i] = As[ty * 8 + i][kk];
            #pragma unroll
            for (int j = 0; j < 8; ++j) wv[j] = Ws[kk][tx + 16 * j];
            #pragma unroll
            for (int i = 0; i < 8; ++i)
                #pragma unroll
                for (int j = 0; j < 8; ++j)
                    acc[i][j] = fmaf(av[i], wv[j], acc[i][j]);
        }
    }

    #pragma unroll
    for (int j = 0; j < 8; ++j) {
        float b = bl[tx + 16 * j];
        #pragma unroll
        for (int i = 0; i < 8; ++i) {
            int r = row0 + ty * 8 + i;
            if (r < n)
                h[(size_t)r * 128 + tx + 16 * j] = fmaxf(acc[i][j] + b, 0.0f);
        }
    }
}

// ---- layer 2 GEMM: out = [agg|h] @ [Wl2;Wr2] + bl2, 128x64 tile ------------

__global__ __launch_bounds__(256) void sage_gemm2(
    const float* __restrict__ agg, const float* __restrict__ hin,
    const float* __restrict__ Wl, const float* __restrict__ Wr,
    const float* __restrict__ bl, float* __restrict__ out, int n)
{
    __shared__ float As[128][33];
    __shared__ float Ws[32][68];
    const int tid = threadIdx.x;
    const int tx = tid & 15;        // col group (cols tx + 16j, j<4)
    const int ty = tid >> 4;        // row group (rows ty*8 + i)
    const int row0 = blockIdx.x * 128;

    const int srow = tid >> 1;
    const int sseg = (tid & 1) * 16;
    const int wkk  = tid >> 3;          // 0..31
    const int wseg = (tid & 7) * 8;     // 0..56

    float acc[8][4];
    #pragma unroll
    for (int i = 0; i < 8; ++i)
        #pragma unroll
        for (int j = 0; j < 4; ++j) acc[i][j] = 0.0f;

    for (int c = 0; c < 8; ++c) {
        const float* Asrc = (c < 4) ? agg : hin;
        const float* Wsrc = (c < 4) ? Wl : Wr;
        const int k0 = (c & 3) * 32;

        int gr = row0 + srow; if (gr >= n) gr = n - 1;
        const float4* ap = (const float4*)(Asrc + (size_t)gr * D + k0 + sseg);
        float4 a0 = ap[0], a1 = ap[1], a2 = ap[2], a3 = ap[3];
        const float4* wp = (const float4*)(Wsrc + (size_t)(k0 + wkk) * 64 + wseg);
        float4 w0 = wp[0], w1 = wp[1];

        __syncthreads();
        {
            float* ad = &As[srow][sseg];
            ad[0]=a0.x; ad[1]=a0.y; ad[2]=a0.z; ad[3]=a0.w;
            ad[4]=a1.x; ad[5]=a1.y; ad[6]=a1.z; ad[7]=a1.w;
            ad[8]=a2.x; ad[9]=a2.y; ad[10]=a2.z; ad[11]=a2.w;
            ad[12]=a3.x; ad[13]=a3.y; ad[14]=a3.z; ad[15]=a3.w;
            float* wd = &Ws[wkk][wseg];
            wd[0]=w0.x; wd[1]=w0.y; wd[2]=w0.z; wd[3]=w0.w;
            wd[4]=w1.x; wd[5]=w1.y; wd[6]=w1.z; wd[7]=w1.w;
        }
        __syncthreads();

        #pragma unroll 8
        for (int kk = 0; kk < 32; ++kk) {
            float av[8], wv[4];
            #pragma unroll
            for (int i = 0; i < 8; ++i) av[i] = As[ty * 8 + i][kk];
            #pragma unroll
            for (int j = 0; j < 4; ++j) wv[j] = Ws[kk][tx + 16 * j];
            #pragma unroll
            for (int i = 0; i < 8; ++i)
                #pragma unroll
                for (int j = 0; j < 4; ++j)
                    acc[i][j] = fmaf(av[i], wv[j], acc[i][j]);
        }
    }

    #pragma unroll
    for (int j = 0; j < 4; ++j) {
        float b = bl[tx + 16 * j];
        #pragma unroll
        for (int i = 0; i < 8; ++i) {
            int r = row0 + ty * 8 + i;
            if (r < n)
                out[(size_t)r * 64 + tx + 16 * j] = acc[i][j] + b;
        }
    }
}

// ----------------------------------------------------------------------------

extern "C" void kernel_launch(void* const* d_in, const int* in_sizes, int n_in,
                              void* d_out, int out_size, void* d_ws, size_t ws_size,
                              hipStream_t stream) {
    const float* x   = (const float*)d_in[0];
    const float* Wl1 = (const float*)d_in[1];
    const float* bl1 = (const float*)d_in[2];
    const float* Wr1 = (const float*)d_in[3];
    const float* Wl2 = (const float*)d_in[4];
    const float* bl2 = (const float*)d_in[5];
    const float* Wr2 = (const float*)d_in[6];
    const int*   ei  = (const int*)d_in[7];

    const int n = in_sizes[0] / D;      // 50000
    const int E = in_sizes[7] / 2;      // 800000
    const int* src = ei;
    const int* dst = ei + E;

    float* out = (float*)d_out;
    char* ws = (char*)d_ws;
    size_t off = 0;
    const size_t feat_bytes = (size_t)n * D * sizeof(float);
    float* agg     = (float*)(ws + off); off += feat_bytes;
    float* h       = (float*)(ws + off); off += feat_bytes;
    int*   row_ptr = (int*)(ws + off);   off += (size_t)(n + 1) * sizeof(int);
    int*   cursor  = (int*)(ws + off);   off += (size_t)n * sizeof(int);
    int*   cnt     = (int*)(ws + off);   off += (size_t)n * sizeof(int);
    int*   ebuf    = (int*)(ws + off);   off += (size_t)E * sizeof(int);

    // ---- CSR build (once; shared by both layers) ----
    hipMemsetAsync(cnt, 0, (size_t)n * sizeof(int), stream);
    hist_dst<<<(E + 255) / 256, 256, 0, stream>>>(dst, cnt, E);
    scan_rowptr<<<1, 256, 0, stream>>>(cnt, row_ptr, cursor, n);
    fill_csr<<<(E + 255) / 256, 256, 0, stream>>>(src, dst, cursor, ebuf, E);

    const int gemm_blocks = (n + 127) / 128;

    // ---- layer 1 ----
    {
        long long total = (long long)n * 64;
        csr_mean_agg128<<<(int)((total + 255) / 256), 256, 0, stream>>>(
            x, row_ptr, ebuf, agg, n);
    }
    sage_gemm1<<<gemm_blocks, 256, 0, stream>>>(agg, x, Wl1, Wr1, bl1, h, n);

    // ---- layer 2 ----
    {
        long long total = (long long)n * 64;
        csr_mean_agg128<<<(int)((total + 255) / 256), 256, 0, stream>>>(
            h, row_ptr, ebuf, agg, n);
    }
    sage_gemm2<<<gemm_blocks, 256, 0, stream>>>(agg, h, Wl2, Wr2, bl2, out, n);
}

// Round 5
// 408.391 us; speedup vs baseline: 4.2347x; 1.2733x over previous
//
#include <hip/hip_runtime.h>

#define D 128

// ---- CSR build -------------------------------------------------------------

__global__ __launch_bounds__(256) void hist_dst(
    const int* __restrict__ dst, int* __restrict__ cnt, int E)
{
    int e = blockIdx.x * blockDim.x + threadIdx.x;
    if (e < E) atomicAdd(&cnt[dst[e]], 1);
}

// stage 1: per-block (256-node) sums
__global__ __launch_bounds__(256) void block_sum(
    const int* __restrict__ cnt, int* __restrict__ blk_sum, int n)
{
    __shared__ int s[256];
    int t = threadIdx.x;
    int i = blockIdx.x * 256 + t;
    s[t] = (i < n) ? cnt[i] : 0;
    __syncthreads();
    #pragma unroll
    for (int off = 128; off > 0; off >>= 1) {
        if (t < off) s[t] += s[t + off];
        __syncthreads();
    }
    if (t == 0) blk_sum[blockIdx.x] = s[0];
}

// stage 2: single-block exclusive scan of block sums (B <= 256)
__global__ __launch_bounds__(256) void scan_blocks(
    const int* __restrict__ blk_sum, int* __restrict__ blk_off,
    int* __restrict__ row_ptr, int B, int n, int E)
{
    __shared__ int s[256];
    int t = threadIdx.x;
    int v = (t < B) ? blk_sum[t] : 0;
    s[t] = v;
    __syncthreads();
    #pragma unroll
    for (int off = 1; off < 256; off <<= 1) {
        int add = (t >= off) ? s[t - off] : 0;
        __syncthreads();
        s[t] += add;
        __syncthreads();
    }
    if (t < B) blk_off[t] = s[t] - v;
    if (t == 0) row_ptr[n] = E;
}

// stage 3: intra-block exclusive scan + block offset -> row_ptr, cursor
__global__ __launch_bounds__(256) void scan_final(
    const int* __restrict__ cnt, const int* __restrict__ blk_off,
    int* __restrict__ row_ptr, int* __restrict__ cursor, int n)
{
    __shared__ int s[256];
    int t = threadIdx.x;
    int i = blockIdx.x * 256 + t;
    int c = (i < n) ? cnt[i] : 0;
    s[t] = c;
    __syncthreads();
    #pragma unroll
    for (int off = 1; off < 256; off <<= 1) {
        int add = (t >= off) ? s[t - off] : 0;
        __syncthreads();
        s[t] += add;
        __syncthreads();
    }
    if (i < n) {
        int v = blk_off[blockIdx.x] + s[t] - c;
        row_ptr[i] = v;
        cursor[i] = v;
    }
}

__global__ __launch_bounds__(256) void fill_csr(
    const int* __restrict__ src, const int* __restrict__ dst,
    int* __restrict__ cursor, int* __restrict__ ebuf, int E)
{
    int e = blockIdx.x * blockDim.x + threadIdx.x;
    if (e >= E) return;
    int pos = atomicAdd(&cursor[dst[e]], 1);
    ebuf[pos] = src[e];
}

// ---- gather mean-aggregate (D=128, one 64-lane wave per node) --------------

__global__ __launch_bounds__(256) void csr_mean_agg128(
    const float* __restrict__ feat, const int* __restrict__ row_ptr,
    const int* __restrict__ ebuf, float* __restrict__ agg, int n)
{
    int gid = blockIdx.x * blockDim.x + threadIdx.x;
    int node = gid >> 6;
    int lane = gid & 63;
    if (node >= n) return;
    int start = row_ptr[node];
    int end = row_ptr[node + 1];
    float ax = 0.0f, ay = 0.0f;
    for (int j0 = start; j0 < end; j0 += 64) {
        int m = min(64, end - j0);
        int myid = (lane < m) ? ebuf[j0 + lane] : 0;
        #pragma unroll 4
        for (int j = 0; j < m; ++j) {
            int s = __shfl(myid, j);
            float2 v = ((const float2*)(feat + (size_t)s * D))[lane];
            ax += v.x; ay += v.y;
        }
    }
    float inv = 1.0f / fmaxf((float)(end - start), 1.0f);
    ((float2*)(agg + (size_t)node * D))[lane] = make_float2(ax * inv, ay * inv);
}

// ---- layer 1 GEMM: h = relu([agg|x] @ [Wl;Wr] + bl), 128x128 tile ----------

__global__ __launch_bounds__(256) void sage_gemm1(
    const float* __restrict__ agg, const float* __restrict__ x,
    const float* __restrict__ Wl, const float* __restrict__ Wr,
    const float* __restrict__ bl, float* __restrict__ h, int n)
{
    __shared__ float As[128][33];
    __shared__ float Ws[32][132];
    const int tid = threadIdx.x;
    const int tx = tid & 15;
    const int ty = tid >> 4;
    const int row0 = blockIdx.x * 128;

    const int srow = tid >> 1;
    const int sseg = (tid & 1) * 16;
    const int wkk  = tid >> 3;
    const int wseg = (tid & 7) * 16;

    float acc[8][8];
    #pragma unroll
    for (int i = 0; i < 8; ++i)
        #pragma unroll
        for (int j = 0; j < 8; ++j) acc[i][j] = 0.0f;

    for (int c = 0; c < 8; ++c) {
        const float* Asrc = (c < 4) ? agg : x;
        const float* Wsrc = (c < 4) ? Wl : Wr;
        const int k0 = (c & 3) * 32;

        int gr = row0 + srow; if (gr >= n) gr = n - 1;
        const float4* ap = (const float4*)(Asrc + (size_t)gr * D + k0 + sseg);
        float4 a0 = ap[0], a1 = ap[1], a2 = ap[2], a3 = ap[3];
        const float4* wp = (const float4*)(Wsrc + (size_t)(k0 + wkk) * 128 + wseg);
        float4 w0 = wp[0], w1 = wp[1], w2 = wp[2], w3 = wp[3];

        __syncthreads();
        {
            float* ad = &As[srow][sseg];
            ad[0]=a0.x; ad[1]=a0.y; ad[2]=a0.z; ad[3]=a0.w;
            ad[4]=a1.x; ad[5]=a1.y; ad[6]=a1.z; ad[7]=a1.w;
            ad[8]=a2.x; ad[9]=a2.y; ad[10]=a2.z; ad[11]=a2.w;
            ad[12]=a3.x; ad[13]=a3.y; ad[14]=a3.z; ad[15]=a3.w;
            float* wd = &Ws[wkk][wseg];
            wd[0]=w0.x; wd[1]=w0.y; wd[2]=w0.z; wd[3]=w0.w;
            wd[4]=w1.x; wd[5]=w1.y; wd[6]=w1.z; wd[7]=w1.w;
            wd[8]=w2.x; wd[9]=w2.y; wd[10]=w2.z; wd[11]=w2.w;
            wd[12]=w3.x; wd[13]=w3.y; wd[14]=w3.z; wd[15]=w3.w;
        }
        __syncthreads();

        #pragma unroll 8
        for (int kk = 0; kk < 32; ++kk) {
            float av[8], wv[8];
            #pragma unroll
            for (int i = 0; i < 8; ++i) av[i] = As[ty * 8 + i][kk];
            #pragma unroll
            for (int j = 0; j < 8; ++j) wv[j] = Ws[kk][tx + 16 * j];
            #pragma unroll
            for (int i = 0; i < 8; ++i)
                #pragma unroll
                for (int j = 0; j < 8; ++j)
                    acc[i][j] = fmaf(av[i], wv[j], acc[i][j]);
        }
    }

    #pragma unroll
    for (int j = 0; j < 8; ++j) {
        float b = bl[tx + 16 * j];
        #pragma unroll
        for (int i = 0; i < 8; ++i) {
            int r = row0 + ty * 8 + i;
            if (r < n)
                h[(size_t)r * 128 + tx + 16 * j] = fmaxf(acc[i][j] + b, 0.0f);
        }
    }
}

// ---- layer 2 GEMM: out = [agg|h] @ [Wl2;Wr2] + bl2, 128x64 tile ------------

__global__ __launch_bounds__(256) void sage_gemm2(
    const float* __restrict__ agg, const float* __restrict__ hin,
    const float* __restrict__ Wl, const float* __restrict__ Wr,
    const float* __restrict__ bl, float* __restrict__ out, int n)
{
    __shared__ float As[128][33];
    __shared__ float Ws[32][68];
    const int tid = threadIdx.x;
    const int tx = tid & 15;
    const int ty = tid >> 4;
    const int row0 = blockIdx.x * 128;

    const int srow = tid >> 1;
    const int sseg = (tid & 1) * 16;
    const int wkk  = tid >> 3;
    const int wseg = (tid & 7) * 8;

    float acc[8][4];
    #pragma unroll
    for (int i = 0; i < 8; ++i)
        #pragma unroll
        for (int j = 0; j < 4; ++j) acc[i][j] = 0.0f;

    for (int c = 0; c < 8; ++c) {
        const float* Asrc = (c < 4) ? agg : hin;
        const float* Wsrc = (c < 4) ? Wl : Wr;
        const int k0 = (c & 3) * 32;

        int gr = row0 + srow; if (gr >= n) gr = n - 1;
        const float4* ap = (const float4*)(Asrc + (size_t)gr * D + k0 + sseg);
        float4 a0 = ap[0], a1 = ap[1], a2 = ap[2], a3 = ap[3];
        const float4* wp = (const float4*)(Wsrc + (size_t)(k0 + wkk) * 64 + wseg);
        float4 w0 = wp[0], w1 = wp[1];

        __syncthreads();
        {
            float* ad = &As[srow][sseg];
            ad[0]=a0.x; ad[1]=a0.y; ad[2]=a0.z; ad[3]=a0.w;
            ad[4]=a1.x; ad[5]=a1.y; ad[6]=a1.z; ad[7]=a1.w;
            ad[8]=a2.x; ad[9]=a2.y; ad[10]=a2.z; ad[11]=a2.w;
            ad[12]=a3.x; ad[13]=a3.y; ad[14]=a3.z; ad[15]=a3.w;
            float* wd = &Ws[wkk][wseg];
            wd[0]=w0.x; wd[1]=w0.y; wd[2]=w0.z; wd[3]=w0.w;
            wd[4]=w1.x; wd[5]=w1.y; wd[6]=w1.z; wd[7]=w1.w;
        }
        __syncthreads();

        #pragma unroll 8
        for (int kk = 0; kk < 32; ++kk) {
            float av[8], wv[4];
            #pragma unroll
            for (int i = 0; i < 8; ++i) av[i] = As[ty * 8 + i][kk];
            #pragma unroll
            for (int j = 0; j < 4; ++j) wv[j] = Ws[kk][tx + 16 * j];
            #pragma unroll
            for (int i = 0; i < 8; ++i)
                #pragma unroll
                for (int j = 0; j < 4; ++j)
                    acc[i][j] = fmaf(av[i], wv[j], acc[i][j]);
        }
    }

    #pragma unroll
    for (int j = 0; j < 4; ++j) {
        float b = bl[tx + 16 * j];
        #pragma unroll
        for (int i = 0; i < 8; ++i) {
            int r = row0 + ty * 8 + i;
            if (r < n)
                out[(size_t)r * 64 + tx + 16 * j] = acc[i][j] + b;
        }
    }
}

// ----------------------------------------------------------------------------

extern "C" void kernel_launch(void* const* d_in, const int* in_sizes, int n_in,
                              void* d_out, int out_size, void* d_ws, size_t ws_size,
                              hipStream_t stream) {
    const float* x   = (const float*)d_in[0];
    const float* Wl1 = (const float*)d_in[1];
    const float* bl1 = (const float*)d_in[2];
    const float* Wr1 = (const float*)d_in[3];
    const float* Wl2 = (const float*)d_in[4];
    const float* bl2 = (const float*)d_in[5];
    const float* Wr2 = (const float*)d_in[6];
    const int*   ei  = (const int*)d_in[7];

    const int n = in_sizes[0] / D;      // 50000
    const int E = in_sizes[7] / 2;      // 800000
    const int* src = ei;
    const int* dst = ei + E;

    float* out = (float*)d_out;
    char* ws = (char*)d_ws;
    size_t off = 0;
    const size_t feat_bytes = (size_t)n * D * sizeof(float);
    float* agg     = (float*)(ws + off); off += feat_bytes;
    float* h       = (float*)(ws + off); off += feat_bytes;
    int*   row_ptr = (int*)(ws + off);   off += (size_t)(n + 1) * sizeof(int);
    int*   cursor  = (int*)(ws + off);   off += (size_t)n * sizeof(int);
    int*   cnt     = (int*)(ws + off);   off += (size_t)n * sizeof(int);
    int*   blk     = (int*)(ws + off);   off += 512 * sizeof(int);  // blk_sum|blk_off
    int*   ebuf    = (int*)(ws + off);   off += (size_t)E * sizeof(int);

    const int B = (n + 255) / 256;      // 196 <= 256
    int* blk_sum = blk;
    int* blk_off = blk + 256;

    // ---- CSR build (once; shared by both layers) ----
    hipMemsetAsync(cnt, 0, (size_t)n * sizeof(int), stream);
    hist_dst<<<(E + 255) / 256, 256, 0, stream>>>(dst, cnt, E);
    block_sum<<<B, 256, 0, stream>>>(cnt, blk_sum, n);
    scan_blocks<<<1, 256, 0, stream>>>(blk_sum, blk_off, row_ptr, B, n, E);
    scan_final<<<B, 256, 0, stream>>>(cnt, blk_off, row_ptr, cursor, n);
    fill_csr<<<(E + 255) / 256, 256, 0, stream>>>(src, dst, cursor, ebuf, E);

    const int gemm_blocks = (n + 127) / 128;

    // ---- layer 1 ----
    {
        long long total = (long long)n * 64;
        csr_mean_agg128<<<(int)((total + 255) / 256), 256, 0, stream>>>(
            x, row_ptr, ebuf, agg, n);
    }
    sage_gemm1<<<gemm_blocks, 256, 0, stream>>>(agg, x, Wl1, Wr1, bl1, h, n);

    // ---- layer 2 ----
    {
        long long total = (long long)n * 64;
        csr_mean_agg128<<<(int)((total + 255) / 256), 256, 0, stream>>>(
            h, row_ptr, ebuf, agg, n);
    }
    sage_gemm2<<<gemm_blocks, 256, 0, stream>>>(agg, h, Wl2, Wr2, bl2, out, n);
}

// Round 6
// 374.049 us; speedup vs baseline: 4.6235x; 1.0918x over previous
//
#include <hip/hip_runtime.h>

#define D 128

__device__ __forceinline__ float bf16_to_f32(unsigned short u) {
    union { unsigned int i; float f; } c; c.i = ((unsigned int)u) << 16; return c.f;
}
__device__ __forceinline__ unsigned short f32_to_bf16(float f) {
    union { float f; unsigned int i; } c; c.f = f;
    unsigned int r = c.i + 0x7fffu + ((c.i >> 16) & 1u);
    return (unsigned short)(r >> 16);
}

// ---- CSR build -------------------------------------------------------------

__global__ __launch_bounds__(256) void hist_dst(
    const int* __restrict__ dst, int* __restrict__ cnt, int E)
{
    int e = blockIdx.x * blockDim.x + threadIdx.x;
    if (e < E) atomicAdd(&cnt[dst[e]], 1);
}

__global__ __launch_bounds__(256) void block_sum(
    const int* __restrict__ cnt, int* __restrict__ blk_sum, int n)
{
    __shared__ int s[256];
    int t = threadIdx.x;
    int i = blockIdx.x * 256 + t;
    s[t] = (i < n) ? cnt[i] : 0;
    __syncthreads();
    #pragma unroll
    for (int off = 128; off > 0; off >>= 1) {
        if (t < off) s[t] += s[t + off];
        __syncthreads();
    }
    if (t == 0) blk_sum[blockIdx.x] = s[0];
}

__global__ __launch_bounds__(256) void scan_blocks(
    const int* __restrict__ blk_sum, int* __restrict__ blk_off,
    int* __restrict__ row_ptr, int B, int n, int E)
{
    __shared__ int s[256];
    int t = threadIdx.x;
    int v = (t < B) ? blk_sum[t] : 0;
    s[t] = v;
    __syncthreads();
    #pragma unroll
    for (int off = 1; off < 256; off <<= 1) {
        int add = (t >= off) ? s[t - off] : 0;
        __syncthreads();
        s[t] += add;
        __syncthreads();
    }
    if (t < B) blk_off[t] = s[t] - v;
    if (t == 0) row_ptr[n] = E;
}

__global__ __launch_bounds__(256) void scan_final(
    const int* __restrict__ cnt, const int* __restrict__ blk_off,
    int* __restrict__ row_ptr, int* __restrict__ cursor, int n)
{
    __shared__ int s[256];
    int t = threadIdx.x;
    int i = blockIdx.x * 256 + t;
    int c = (i < n) ? cnt[i] : 0;
    s[t] = c;
    __syncthreads();
    #pragma unroll
    for (int off = 1; off < 256; off <<= 1) {
        int add = (t >= off) ? s[t - off] : 0;
        __syncthreads();
        s[t] += add;
        __syncthreads();
    }
    if (i < n) {
        int v = blk_off[blockIdx.x] + s[t] - c;
        row_ptr[i] = v;
        cursor[i] = v;
    }
}

__global__ __launch_bounds__(256) void fill_csr(
    const int* __restrict__ src, const int* __restrict__ dst,
    int* __restrict__ cursor, int* __restrict__ ebuf, int E)
{
    int e = blockIdx.x * blockDim.x + threadIdx.x;
    if (e >= E) return;
    int pos = atomicAdd(&cursor[dst[e]], 1);
    ebuf[pos] = src[e];
}

// ---- GEMM 1: Pl(bf16) = x@Wl1, Pr(f32) = x@Wr1; BM=64, BN=256, BK=32 -------

__global__ __launch_bounds__(256) void gemm_x(
    const float* __restrict__ x, const float* __restrict__ Wl,
    const float* __restrict__ Wr, unsigned short* __restrict__ Pl,
    float* __restrict__ Pr, int n)
{
    __shared__ float As[64][33];
    __shared__ float Ws[32][264];     // 8 col-groups of 32; store col^group swizzle
    const int tid = threadIdx.x;
    const int tx = tid & 31;
    const int ty = tid >> 5;          // 0..7 -> rows ty*8+i
    const int row0 = blockIdx.x * 64;

    const int arow = tid >> 2;        // 0..63
    const int aseg = (tid & 3) * 8;
    const int wrow = tid >> 3;        // 0..31
    const int wt   = tid & 7;         // col group
    const float* wbase = (wt < 4) ? (Wl + wt * 32) : (Wr + (wt - 4) * 32);

    float acc[8][8];
    #pragma unroll
    for (int i = 0; i < 8; ++i)
        #pragma unroll
        for (int j = 0; j < 8; ++j) acc[i][j] = 0.0f;

    for (int c = 0; c < 4; ++c) {
        const int k0 = c * 32;
        int gr = row0 + arow; if (gr >= n) gr = n - 1;
        const float4* ap = (const float4*)(x + (size_t)gr * D + k0 + aseg);
        float4 a0 = ap[0], a1 = ap[1];
        const float4* wp = (const float4*)(wbase + (size_t)(k0 + wrow) * D);
        float4 wrg[8];
        #pragma unroll
        for (int q = 0; q < 8; ++q) wrg[q] = wp[q];

        __syncthreads();
        {
            float* ad = &As[arow][aseg];
            ad[0]=a0.x; ad[1]=a0.y; ad[2]=a0.z; ad[3]=a0.w;
            ad[4]=a1.x; ad[5]=a1.y; ad[6]=a1.z; ad[7]=a1.w;
            float* wd = &Ws[wrow][wt * 32];
            #pragma unroll
            for (int q = 0; q < 8; ++q) {
                wd[(4*q+0) ^ wt] = wrg[q].x;
                wd[(4*q+1) ^ wt] = wrg[q].y;
                wd[(4*q+2) ^ wt] = wrg[q].z;
                wd[(4*q+3) ^ wt] = wrg[q].w;
            }
        }
        __syncthreads();

        #pragma unroll 4
        for (int kk = 0; kk < 32; ++kk) {
            float av[8], wv[8];
            #pragma unroll
            for (int i = 0; i < 8; ++i) av[i] = As[ty * 8 + i][kk];
            #pragma unroll
            for (int j = 0; j < 8; ++j) wv[j] = Ws[kk][32 * j + (tx ^ j)];
            #pragma unroll
            for (int i = 0; i < 8; ++i)
                #pragma unroll
                for (int j = 0; j < 8; ++j)
                    acc[i][j] = fmaf(av[i], wv[j], acc[i][j]);
        }
    }

    #pragma unroll
    for (int i = 0; i < 8; ++i) {
        int r = row0 + ty * 8 + i;
        if (r < n) {
            #pragma unroll
            for (int j = 0; j < 4; ++j)
                Pl[(size_t)r * 128 + tx + 32 * j] = f32_to_bf16(acc[i][j]);
            #pragma unroll
            for (int j = 0; j < 4; ++j)
                Pr[(size_t)r * 128 + tx + 32 * j] = acc[i][4 + j];
        }
    }
}

// ---- agg1: h = relu(mean_gather(Pl) + Pr + b1); one wave per node ----------

__global__ __launch_bounds__(256) void agg_relu1(
    const unsigned short* __restrict__ Pl, const float* __restrict__ Pr,
    const float* __restrict__ b, const int* __restrict__ row_ptr,
    const int* __restrict__ ebuf, float* __restrict__ h, int n)
{
    int gid = blockIdx.x * blockDim.x + threadIdx.x;
    int node = gid >> 6;
    int lane = gid & 63;
    if (node >= n) return;
    int start = row_ptr[node];
    int end = row_ptr[node + 1];
    float ax = 0.0f, ay = 0.0f;
    for (int j0 = start; j0 < end; j0 += 64) {
        int m = min(64, end - j0);
        int myid = (lane < m) ? ebuf[j0 + lane] : 0;
        #pragma unroll 4
        for (int j = 0; j < m; ++j) {
            int s = __shfl(myid, j);
            unsigned int v = *(const unsigned int*)(Pl + (size_t)s * 128 + 2 * lane);
            ax += bf16_to_f32((unsigned short)(v & 0xffff));
            ay += bf16_to_f32((unsigned short)(v >> 16));
        }
    }
    float inv = 1.0f / fmaxf((float)(end - start), 1.0f);
    float2 pr = *(const float2*)(Pr + (size_t)node * 128 + 2 * lane);
    float2 bb = *(const float2*)(b + 2 * lane);
    float2 o;
    o.x = fmaxf(ax * inv + pr.x + bb.x, 0.0f);
    o.y = fmaxf(ay * inv + pr.y + bb.y, 0.0f);
    *(float2*)(h + (size_t)node * 128 + 2 * lane) = o;
}

// ---- GEMM 2: Ql(bf16) = h@Wl2, Qr(f32) = h@Wr2; BM=64, BN=128, BK=32 -------

__global__ __launch_bounds__(256) void gemm_h(
    const float* __restrict__ hin, const float* __restrict__ Wl,
    const float* __restrict__ Wr, unsigned short* __restrict__ Ql,
    float* __restrict__ Qr, int n)
{
    __shared__ float As[64][33];
    __shared__ float Ws[32][136];     // 8 col-groups of 16; store col^group swizzle
    const int tid = threadIdx.x;
    const int tx = tid & 31;
    const int ty = tid >> 5;
    const int row0 = blockIdx.x * 64;

    const int arow = tid >> 2;
    const int aseg = (tid & 3) * 8;
    const int wrow = tid >> 3;        // 0..31
    const int wt   = tid & 7;         // 16-wide col group
    const float* wbase = (wt < 4) ? (Wl + wt * 16) : (Wr + (wt - 4) * 16);

    float acc[8][4];
    #pragma unroll
    for (int i = 0; i < 8; ++i)
        #pragma unroll
        for (int j = 0; j < 4; ++j) acc[i][j] = 0.0f;

    for (int c = 0; c < 4; ++c) {
        const int k0 = c * 32;
        int gr = row0 + arow; if (gr >= n) gr = n - 1;
        const float4* ap = (const float4*)(hin + (size_t)gr * D + k0 + aseg);
        float4 a0 = ap[0], a1 = ap[1];
        const float4* wp = (const float4*)(wbase + (size_t)(k0 + wrow) * 64);
        float4 wrg[4];
        #pragma unroll
        for (int q = 0; q < 4; ++q) wrg[q] = wp[q];

        __syncthreads();
        {
            float* ad = &As[arow][aseg];
            ad[0]=a0.x; ad[1]=a0.y; ad[2]=a0.z; ad[3]=a0.w;
            ad[4]=a1.x; ad[5]=a1.y; ad[6]=a1.z; ad[7]=a1.w;
            float* wd = &Ws[wrow][wt * 16];
            #pragma unroll
            for (int q = 0; q < 4; ++q) {
                wd[(4*q+0) ^ wt] = wrg[q].x;
                wd[(4*q+1) ^ wt] = wrg[q].y;
                wd[(4*q+2) ^ wt] = wrg[q].z;
                wd[(4*q+3) ^ wt] = wrg[q].w;
            }
        }
        __syncthreads();

        #pragma unroll 4
        for (int kk = 0; kk < 32; ++kk) {
            float av[8], wv[4];
            #pragma unroll
            for (int i = 0; i < 8; ++i) av[i] = As[ty * 8 + i][kk];
            #pragma unroll
            for (int j = 0; j < 4; ++j) {
                int g = 2 * j + (tx >> 4);
                wv[j] = Ws[kk][16 * g + ((tx & 15) ^ g)];
            }
            #pragma unroll
            for (int i = 0; i < 8; ++i)
                #pragma unroll
                for (int j = 0; j < 4; ++j)
                    acc[i][j] = fmaf(av[i], wv[j], acc[i][j]);
        }
    }

    #pragma unroll
    for (int i = 0; i < 8; ++i) {
        int r = row0 + ty * 8 + i;
        if (r < n) {
            #pragma unroll
            for (int j = 0; j < 2; ++j)
                Ql[(size_t)r * 64 + tx + 32 * j] = f32_to_bf16(acc[i][j]);
            #pragma unroll
            for (int j = 0; j < 2; ++j)
                Qr[(size_t)r * 64 + tx + 32 * j] = acc[i][2 + j];
        }
    }
}

// ---- agg2: out = mean_gather(Ql) + Qr + b2; one wave per node (64 cols) ----

__global__ __launch_bounds__(256) void agg2(
    const unsigned short* __restrict__ Ql, const float* __restrict__ Qr,
    const float* __restrict__ b, const int* __restrict__ row_ptr,
    const int* __restrict__ ebuf, float* __restrict__ out, int n)
{
    int gid = blockIdx.x * blockDim.x + threadIdx.x;
    int node = gid >> 6;
    int lane = gid & 63;
    if (node >= n) return;
    int start = row_ptr[node];
    int end = row_ptr[node + 1];
    float ax = 0.0f;
    for (int j0 = start; j0 < end; j0 += 64) {
        int m = min(64, end - j0);
        int myid = (lane < m) ? ebuf[j0 + lane] : 0;
        #pragma unroll 4
        for (int j = 0; j < m; ++j) {
            int s = __shfl(myid, j);
            ax += bf16_to_f32(Ql[(size_t)s * 64 + lane]);
        }
    }
    float inv = 1.0f / fmaxf((float)(end - start), 1.0f);
    out[(size_t)node * 64 + lane] = ax * inv + Qr[(size_t)node * 64 + lane] + b[lane];
}

// ----------------------------------------------------------------------------

extern "C" void kernel_launch(void* const* d_in, const int* in_sizes, int n_in,
                              void* d_out, int out_size, void* d_ws, size_t ws_size,
                              hipStream_t stream) {
    const float* x   = (const float*)d_in[0];
    const float* Wl1 = (const float*)d_in[1];
    const float* bl1 = (const float*)d_in[2];
    const float* Wr1 = (const float*)d_in[3];
    const float* Wl2 = (const float*)d_in[4];
    const float* bl2 = (const float*)d_in[5];
    const float* Wr2 = (const float*)d_in[6];
    const int*   ei  = (const int*)d_in[7];

    const int n = in_sizes[0] / D;      // 50000
    const int E = in_sizes[7] / 2;      // 800000
    const int* src = ei;
    const int* dst = ei + E;

    float* out = (float*)d_out;
    char* ws = (char*)d_ws;
    size_t off = 0;
    unsigned short* Pl = (unsigned short*)(ws + off); off += (size_t)n * 128 * 2;  // also Ql
    float* Pr = (float*)(ws + off); off += (size_t)n * 128 * 4;                    // also Qr
    float* h  = (float*)(ws + off); off += (size_t)n * 128 * 4;
    int* row_ptr = (int*)(ws + off); off += (size_t)(n + 1) * 4;
    int* cursor  = (int*)(ws + off); off += (size_t)n * 4;
    int* cnt     = (int*)(ws + off); off += (size_t)n * 4;
    int* blk     = (int*)(ws + off); off += 512 * 4;
    int* ebuf    = (int*)(ws + off); off += (size_t)E * 4;

    unsigned short* Ql = Pl;   // reuse (Pl dead after agg_relu1)
    float* Qr = Pr;            // reuse

    const int B = (n + 255) / 256;
    int* blk_sum = blk;
    int* blk_off = blk + 256;

    // CSR build (shared by both layers)
    hipMemsetAsync(cnt, 0, (size_t)n * sizeof(int), stream);
    hist_dst<<<(E + 255) / 256, 256, 0, stream>>>(dst, cnt, E);
    block_sum<<<B, 256, 0, stream>>>(cnt, blk_sum, n);
    scan_blocks<<<1, 256, 0, stream>>>(blk_sum, blk_off, row_ptr, B, n, E);
    scan_final<<<B, 256, 0, stream>>>(cnt, blk_off, row_ptr, cursor, n);
    fill_csr<<<(E + 255) / 256, 256, 0, stream>>>(src, dst, cursor, ebuf, E);

    const int gblocks = (n + 63) / 64;
    const int ablocks = (int)(((long long)n * 64 + 255) / 256);

    // layer 1
    gemm_x<<<gblocks, 256, 0, stream>>>(x, Wl1, Wr1, Pl, Pr, n);
    agg_relu1<<<ablocks, 256, 0, stream>>>(Pl, Pr, bl1, row_ptr, ebuf, h, n);

    // layer 2
    gemm_h<<<gblocks, 256, 0, stream>>>(h, Wl2, Wr2, Ql, Qr, n);
    agg2<<<ablocks, 256, 0, stream>>>(Ql, Qr, bl2, row_ptr, ebuf, out, n);
}

// Round 16
// 327.409 us; speedup vs baseline: 5.2821x; 1.1425x over previous
//
#include <hip/hip_runtime.h>

#define D 128

__device__ __forceinline__ float bf16_to_f32(unsigned short u) {
    union { unsigned int i; float f; } c; c.i = ((unsigned int)u) << 16; return c.f;
}
__device__ __forceinline__ unsigned short f32_to_bf16(float f) {
    union { float f; unsigned int i; } c; c.f = f;
    unsigned int r = c.i + 0x7fffu + ((c.i >> 16) & 1u);
    return (unsigned short)(r >> 16);
}

// ---- CSR build -------------------------------------------------------------

__global__ __launch_bounds__(256) void hist_dst(
    const int* __restrict__ dst, int* __restrict__ cnt, int E)
{
    int e = blockIdx.x * blockDim.x + threadIdx.x;
    if (e < E) atomicAdd(&cnt[dst[e]], 1);
}

__global__ __launch_bounds__(256) void block_sum(
    const int* __restrict__ cnt, int* __restrict__ blk_sum, int n)
{
    __shared__ int s[256];
    int t = threadIdx.x;
    int i = blockIdx.x * 256 + t;
    s[t] = (i < n) ? cnt[i] : 0;
    __syncthreads();
    #pragma unroll
    for (int off = 128; off > 0; off >>= 1) {
        if (t < off) s[t] += s[t + off];
        __syncthreads();
    }
    if (t == 0) blk_sum[blockIdx.x] = s[0];
}

__global__ __launch_bounds__(256) void scan_blocks(
    const int* __restrict__ blk_sum, int* __restrict__ blk_off,
    int* __restrict__ row_ptr, int B, int n, int E)
{
    __shared__ int s[256];
    int t = threadIdx.x;
    int v = (t < B) ? blk_sum[t] : 0;
    s[t] = v;
    __syncthreads();
    #pragma unroll
    for (int off = 1; off < 256; off <<= 1) {
        int add = (t >= off) ? s[t - off] : 0;
        __syncthreads();
        s[t] += add;
        __syncthreads();
    }
    if (t < B) blk_off[t] = s[t] - v;
    if (t == 0) row_ptr[n] = E;
}

__global__ __launch_bounds__(256) void scan_final(
    const int* __restrict__ cnt, const int* __restrict__ blk_off,
    int* __restrict__ row_ptr, int* __restrict__ cursor, int n)
{
    __shared__ int s[256];
    int t = threadIdx.x;
    int i = blockIdx.x * 256 + t;
    int c = (i < n) ? cnt[i] : 0;
    s[t] = c;
    __syncthreads();
    #pragma unroll
    for (int off = 1; off < 256; off <<= 1) {
        int add = (t >= off) ? s[t - off] : 0;
        __syncthreads();
        s[t] += add;
        __syncthreads();
    }
    if (i < n) {
        int v = blk_off[blockIdx.x] + s[t] - c;
        row_ptr[i] = v;
        cursor[i] = v;
    }
}

__global__ __launch_bounds__(256) void fill_csr(
    const int* __restrict__ src, const int* __restrict__ dst,
    int* __restrict__ cursor, int* __restrict__ ebuf, int E)
{
    int e = blockIdx.x * blockDim.x + threadIdx.x;
    if (e >= E) return;
    int pos = atomicAdd(&cursor[dst[e]], 1);
    ebuf[pos] = src[e];
}

// ---- GEMM 1: Pl(bf16) = x@Wl1, Pr(f32) = x@Wr1; BM=64, BN=256, BK=16 -------

__global__ __launch_bounds__(256) void gemm_x(
    const float* __restrict__ x, const float* __restrict__ Wl,
    const float* __restrict__ Wr, unsigned short* __restrict__ Pl,
    float* __restrict__ Pr, int n)
{
    __shared__ float As[64][17];
    __shared__ float Ws[16][264];
    const int tid = threadIdx.x;
    const int tx = tid & 31;
    const int ty = tid >> 5;          // 0..7 -> rows ty*8+i
    const int row0 = blockIdx.x * 64;

    const int arow = tid >> 2;        // 0..63
    const int aseg = (tid & 3) * 4;   // 0,4,8,12
    const int wrow = tid >> 4;        // 0..15 (k within chunk)
    const int wt   = tid & 15;        // 16-col group
    const int wj   = wt >> 1;         // 32-col super group 0..7
    const int wc0  = (wt & 1) * 16;   // base within super group
    const float* wbase = (wt < 8) ? (Wl + wt * 16) : (Wr + (wt - 8) * 16);

    float acc[8][8];
    #pragma unroll
    for (int i = 0; i < 8; ++i)
        #pragma unroll
        for (int j = 0; j < 8; ++j) acc[i][j] = 0.0f;

    for (int c = 0; c < 8; ++c) {
        const int k0 = c * 16;
        int gr = row0 + arow; if (gr >= n) gr = n - 1;
        float4 a0 = *(const float4*)(x + (size_t)gr * D + k0 + aseg);
        const float4* wp = (const float4*)(wbase + (size_t)(k0 + wrow) * D);
        float4 wrg[4];
        #pragma unroll
        for (int q = 0; q < 4; ++q) wrg[q] = wp[q];

        __syncthreads();
        {
            float* ad = &As[arow][aseg];
            ad[0]=a0.x; ad[1]=a0.y; ad[2]=a0.z; ad[3]=a0.w;
            float* wd = &Ws[wrow][32 * wj];
            #pragma unroll
            for (int q = 0; q < 4; ++q) {
                wd[(wc0 + 4*q+0) ^ wj] = wrg[q].x;
                wd[(wc0 + 4*q+1) ^ wj] = wrg[q].y;
                wd[(wc0 + 4*q+2) ^ wj] = wrg[q].z;
                wd[(wc0 + 4*q+3) ^ wj] = wrg[q].w;
            }
        }
        __syncthreads();

        #pragma unroll 4
        for (int kk = 0; kk < 16; ++kk) {
            float av[8], wv[8];
            #pragma unroll
            for (int i = 0; i < 8; ++i) av[i] = As[ty * 8 + i][kk];
            #pragma unroll
            for (int j = 0; j < 8; ++j) wv[j] = Ws[kk][32 * j + (tx ^ j)];
            #pragma unroll
            for (int i = 0; i < 8; ++i)
                #pragma unroll
                for (int j = 0; j < 8; ++j)
                    acc[i][j] = fmaf(av[i], wv[j], acc[i][j]);
        }
    }

    #pragma unroll
    for (int i = 0; i < 8; ++i) {
        int r = row0 + ty * 8 + i;
        if (r < n) {
            #pragma unroll
            for (int j = 0; j < 4; ++j)
                Pl[(size_t)r * 128 + tx + 32 * j] = f32_to_bf16(acc[i][j]);
            #pragma unroll
            for (int j = 0; j < 4; ++j)
                Pr[(size_t)r * 128 + tx + 32 * j] = acc[i][4 + j];
        }
    }
}

// ---- agg1: h = relu(mean_gather(Pl) + Pr + b1); 32 lanes per node ----------

__global__ __launch_bounds__(256) void agg_relu1(
    const unsigned short* __restrict__ Pl, const float* __restrict__ Pr,
    const float* __restrict__ b, const int* __restrict__ row_ptr,
    const int* __restrict__ ebuf, float* __restrict__ h, int n)
{
    int gid = blockIdx.x * blockDim.x + threadIdx.x;
    int node = gid >> 5;
    int lane = gid & 31;
    if (node >= n) return;
    int start = row_ptr[node];
    int end = row_ptr[node + 1];
    float a0 = 0.0f, a1 = 0.0f, a2 = 0.0f, a3 = 0.0f;
    for (int j0 = start; j0 < end; j0 += 32) {
        int m = min(32, end - j0);
        int myid = (lane < m) ? ebuf[j0 + lane] : 0;
        #pragma unroll 4
        for (int j = 0; j < m; ++j) {
            int s = __shfl(myid, j, 32);
            uint2 v = *(const uint2*)(Pl + (size_t)s * 128 + 4 * lane);
            a0 += bf16_to_f32((unsigned short)(v.x & 0xffff));
            a1 += bf16_to_f32((unsigned short)(v.x >> 16));
            a2 += bf16_to_f32((unsigned short)(v.y & 0xffff));
            a3 += bf16_to_f32((unsigned short)(v.y >> 16));
        }
    }
    float inv = 1.0f / fmaxf((float)(end - start), 1.0f);
    float4 pr = *(const float4*)(Pr + (size_t)node * 128 + 4 * lane);
    float4 bb = *(const float4*)(b + 4 * lane);
    float4 o;
    o.x = fmaxf(a0 * inv + pr.x + bb.x, 0.0f);
    o.y = fmaxf(a1 * inv + pr.y + bb.y, 0.0f);
    o.z = fmaxf(a2 * inv + pr.z + bb.z, 0.0f);
    o.w = fmaxf(a3 * inv + pr.w + bb.w, 0.0f);
    *(float4*)(h + (size_t)node * 128 + 4 * lane) = o;
}

// ---- GEMM 2: Ql(bf16) = h@Wl2, Qr(f32) = h@Wr2; BM=64, BN=128, BK=16 -------

__global__ __launch_bounds__(256) void gemm_h(
    const float* __restrict__ hin, const float* __restrict__ Wl,
    const float* __restrict__ Wr, unsigned short* __restrict__ Ql,
    float* __restrict__ Qr, int n)
{
    __shared__ float As[64][17];
    __shared__ float Ws[16][132];
    const int tid = threadIdx.x;
    const int tx = tid & 31;
    const int ty = tid >> 5;
    const int row0 = blockIdx.x * 64;

    const int arow = tid >> 2;
    const int aseg = (tid & 3) * 4;
    const int wrow = tid >> 4;        // 0..15
    const int wt   = tid & 15;        // 8-col group
    const int wj   = wt >> 2;         // 0..3
    const int wc0  = (wt & 3) * 8;
    const float* wbase = (wt < 8) ? (Wl + wt * 8) : (Wr + (wt - 8) * 8);

    float acc[8][4];
    #pragma unroll
    for (int i = 0; i < 8; ++i)
        #pragma unroll
        for (int j = 0; j < 4; ++j) acc[i][j] = 0.0f;

    for (int c = 0; c < 8; ++c) {
        const int k0 = c * 16;
        int gr = row0 + arow; if (gr >= n) gr = n - 1;
        float4 a0 = *(const float4*)(hin + (size_t)gr * D + k0 + aseg);
        const float4* wp = (const float4*)(wbase + (size_t)(k0 + wrow) * 64);
        float4 w0 = wp[0], w1 = wp[1];

        __syncthreads();
        {
            float* ad = &As[arow][aseg];
            ad[0]=a0.x; ad[1]=a0.y; ad[2]=a0.z; ad[3]=a0.w;
            float* wd = &Ws[wrow][32 * wj];
            wd[(wc0+0) ^ wj] = w0.x;  wd[(wc0+1) ^ wj] = w0.y;
            wd[(wc0+2) ^ wj] = w0.z;  wd[(wc0+3) ^ wj] = w0.w;
            wd[(wc0+4) ^ wj] = w1.x;  wd[(wc0+5) ^ wj] = w1.y;
            wd[(wc0+6) ^ wj] = w1.z;  wd[(wc0+7) ^ wj] = w1.w;
        }
        __syncthreads();

        #pragma unroll 4
        for (int kk = 0; kk < 16; ++kk) {
            float av[8], wv[4];
            #pragma unroll
            for (int i = 0; i < 8; ++i) av[i] = As[ty * 8 + i][kk];
            #pragma unroll
            for (int j = 0; j < 4; ++j) wv[j] = Ws[kk][32 * j + (tx ^ j)];
            #pragma unroll
            for (int i = 0; i < 8; ++i)
                #pragma unroll
                for (int j = 0; j < 4; ++j)
                    acc[i][j] = fmaf(av[i], wv[j], acc[i][j]);
        }
    }

    #pragma unroll
    for (int i = 0; i < 8; ++i) {
        int r = row0 + ty * 8 + i;
        if (r < n) {
            #pragma unroll
            for (int j = 0; j < 2; ++j)
                Ql[(size_t)r * 64 + tx + 32 * j] = f32_to_bf16(acc[i][j]);
            #pragma unroll
            for (int j = 0; j < 2; ++j)
                Qr[(size_t)r * 64 + tx + 32 * j] = acc[i][2 + j];
        }
    }
}

// ---- agg2: out = mean_gather(Ql) + Qr + b2; 16 lanes per node --------------

__global__ __launch_bounds__(256) void agg2(
    const unsigned short* __restrict__ Ql, const float* __restrict__ Qr,
    const float* __restrict__ b, const int* __restrict__ row_ptr,
    const int* __restrict__ ebuf, float* __restrict__ out, int n)
{
    int gid = blockIdx.x * blockDim.x + threadIdx.x;
    int node = gid >> 4;
    int lane = gid & 15;
    if (node >= n) return;
    int start = row_ptr[node];
    int end = row_ptr[node + 1];
    float a0 = 0.0f, a1 = 0.0f, a2 = 0.0f, a3 = 0.0f;
    for (int j0 = start; j0 < end; j0 += 16) {
        int m = min(16, end - j0);
        int myid = (lane < m) ? ebuf[j0 + lane] : 0;
        #pragma unroll 4
        for (int j = 0; j < m; ++j) {
            int s = __shfl(myid, j, 16);
            uint2 v = *(const uint2*)(Ql + (size_t)s * 64 + 4 * lane);
            a0 += bf16_to_f32((unsigned short)(v.x & 0xffff));
            a1 += bf16_to_f32((unsigned short)(v.x >> 16));
            a2 += bf16_to_f32((unsigned short)(v.y & 0xffff));
            a3 += bf16_to_f32((unsigned short)(v.y >> 16));
        }
    }
    float inv = 1.0f / fmaxf((float)(end - start), 1.0f);
    float4 qr = *(const float4*)(Qr + (size_t)node * 64 + 4 * lane);
    float4 bb = *(const float4*)(b + 4 * lane);
    float4 o;
    o.x = a0 * inv + qr.x + bb.x;
    o.y = a1 * inv + qr.y + bb.y;
    o.z = a2 * inv + qr.z + bb.z;
    o.w = a3 * inv + qr.w + bb.w;
    *(float4*)(out + (size_t)node * 64 + 4 * lane) = o;
}

// ----------------------------------------------------------------------------

extern "C" void kernel_launch(void* const* d_in, const int* in_sizes, int n_in,
                              void* d_out, int out_size, void* d_ws, size_t ws_size,
                              hipStream_t stream) {
    const float* x   = (const float*)d_in[0];
    const float* Wl1 = (const float*)d_in[1];
    const float* bl1 = (const float*)d_in[2];
    const float* Wr1 = (const float*)d_in[3];
    const float* Wl2 = (const float*)d_in[4];
    const float* bl2 = (const float*)d_in[5];
    const float* Wr2 = (const float*)d_in[6];
    const int*   ei  = (const int*)d_in[7];

    const int n = in_sizes[0] / D;      // 50000
    const int E = in_sizes[7] / 2;      // 800000
    const int* src = ei;
    const int* dst = ei + E;

    float* out = (float*)d_out;
    char* ws = (char*)d_ws;
    size_t off = 0;
    unsigned short* Pl = (unsigned short*)(ws + off); off += (size_t)n * 128 * 2;  // also Ql
    float* Pr = (float*)(ws + off); off += (size_t)n * 128 * 4;                    // also Qr
    float* h  = (float*)(ws + off); off += (size_t)n * 128 * 4;
    int* row_ptr = (int*)(ws + off); off += (size_t)(n + 1) * 4;
    int* cursor  = (int*)(ws + off); off += (size_t)n * 4;
    int* cnt     = (int*)(ws + off); off += (size_t)n * 4;
    int* blk     = (int*)(ws + off); off += 512 * 4;
    int* ebuf    = (int*)(ws + off); off += (size_t)E * 4;

    unsigned short* Ql = Pl;   // reuse (Pl dead after agg_relu1)
    float* Qr = Pr;            // reuse

    const int B = (n + 255) / 256;
    int* blk_sum = blk;
    int* blk_off = blk + 256;

    // CSR build (shared by both layers)
    hipMemsetAsync(cnt, 0, (size_t)n * sizeof(int), stream);
    hist_dst<<<(E + 255) / 256, 256, 0, stream>>>(dst, cnt, E);
    block_sum<<<B, 256, 0, stream>>>(cnt, blk_sum, n);
    scan_blocks<<<1, 256, 0, stream>>>(blk_sum, blk_off, row_ptr, B, n, E);
    scan_final<<<B, 256, 0, stream>>>(cnt, blk_off, row_ptr, cursor, n);
    fill_csr<<<(E + 255) / 256, 256, 0, stream>>>(src, dst, cursor, ebuf, E);

    const int gblocks = (n + 63) / 64;

    // layer 1
    gemm_x<<<gblocks, 256, 0, stream>>>(x, Wl1, Wr1, Pl, Pr, n);
    {
        long long total = (long long)n * 32;
        agg_relu1<<<(int)((total + 255) / 256), 256, 0, stream>>>(
            Pl, Pr, bl1, row_ptr, ebuf, h, n);
    }

    // layer 2
    gemm_h<<<gblocks, 256, 0, stream>>>(h, Wl2, Wr2, Ql, Qr, n);
    {
        long long total = (long long)n * 16;
        agg2<<<(int)((total + 255) / 256), 256, 0, stream>>>(
            Ql, Qr, bl2, row_ptr, ebuf, out, n);
    }
}